// Round 7
// baseline (162.358 us; speedup 1.0000x reference)
//
#include <hip/hip_runtime.h>
#include <hip/hip_fp16.h>

// N=1536 T=20 H=64 E=16 M=128
// pre1[i,j] = Q[j] - P[i]  (Q,P: N x 128 fp16 in d_ws; W2T: 64x128 fp16 in d_ws)
// out[i]    = max_j relu( relu(Q[j]-P[i]) @ W2 + b2 )
//
// R7: NI=1 per wave — the ONLY config whose combined reg set (bfrag 64 + pv 16
// + q 16 + acc 16 + misc ~12 ≈ 124) fits 4 waves/SIMD (<=128). Calibrated model
// (R6): one 16x16x32 MFMA = ~16 cyc/SIMD pipe; R4's MfmaUtil 30% == exactly
// 2 waves/SIMD issuing; saturation needs 3-4 waves/SIMD x ~70% MFMA duty.
// 256-thr blocks = 4 waves = 4 consecutive i's (share q-tiles via L1, dodge
// wg/CU dispatch cap). JSPLIT=8 -> 3072 blocks = 12 blocks/CU: divisible by
// 4-resident (<=128 regs) AND 3-resident (<=170) -> zero tail either way.

#define NN 1536
#define HH 64
#define EE 16
#define MM 128
#define TT 20
#define JSPLIT 8
#define NIGRP (NN / 4)       // 384 i-groups (4 i's per block, 1 per wave)
#define NTILE (96 / JSPLIT)  // 12 j-tiles of 16 per wave

typedef _Float16 half8 __attribute__((ext_vector_type(8)));
typedef _Float16 half2v __attribute__((ext_vector_type(2)));
typedef float f32x4 __attribute__((ext_vector_type(4)));

union H8 { half8 v; half2v h2[4]; };

// grid NN, block 128. Computes Q,P,W2T (fp16) and zero-inits out (poisoned 0xAA).
__global__ __launch_bounds__(128) void precompute_kernel(
    const float* __restrict__ hidden, const float* __restrict__ gt,
    const float* __restrict__ We, const float* __restrict__ be,
    const float* __restrict__ W1, const float* __restrict__ b1,
    const float* __restrict__ W2,
    _Float16* __restrict__ Q, _Float16* __restrict__ P,
    _Float16* __restrict__ W2T, float* __restrict__ out)
{
  const int j = blockIdx.x;
  const int m = threadIdx.x;
  const float* hrow = hidden + j * HH;
  float a = 0.f;
  #pragma unroll 8
  for (int h = 0; h < HH; ++h) a = fmaf(hrow[h], W1[h * MM + m], a);
  float ve0 = 0.f, ve1 = 0.f, cm = b1[m];
  #pragma unroll
  for (int e = 0; e < EE; ++e) {
    float w1e = W1[(HH + e) * MM + m];
    ve0 = fmaf(We[e], w1e, ve0);       // We[0][e]
    ve1 = fmaf(We[EE + e], w1e, ve1);  // We[1][e]
    cm  = fmaf(be[e], w1e, cm);
  }
  const float e0 = gt[j * (2 * TT) + 2 * (TT - 1)];
  const float e1 = gt[j * (2 * TT) + 2 * (TT - 1) + 1];
  const float p = fmaf(e0, ve0, e1 * ve1);
  P[j * MM + m] = (_Float16)p;
  Q[j * MM + m] = (_Float16)(a + p + cm);
  if (j < HH) W2T[j * MM + m] = (_Float16)W2[m * HH + j];  // W2T[col][k]
  if (m < HH) out[j * HH + m] = 0.f;
}

// grid NIGRP*JSPLIT (=3072), block 256 (4 waves). Wave w: i = ig*4+w, 12 j-tiles.
// (256,3): cap ~170 >> est. live ~124 (R2 lesson: never cap below live set);
// if alloc lands <=128 HW gives 4 waves/SIMD automatically.
__global__ __launch_bounds__(256, 3) void pairmlp_max_kernel(
    const _Float16* __restrict__ Q, const _Float16* __restrict__ P,
    const _Float16* __restrict__ W2T, const float* __restrict__ b2,
    float* __restrict__ out)
{
  const int wave = threadIdx.x >> 6;
  const int lane = threadIdx.x & 63;
  const int quad = lane >> 4;   // 0..3
  const int lcol = lane & 15;
  const int ig = blockIdx.x % NIGRP;
  const int js = blockIdx.x / NIGRP;
  const int i  = ig * 4 + wave;

  // B fragments from fp16 W2T: bfrag[ct][ks] = W2T[ct*16+lcol][ks*32+quad*8 ..+8]
  half8 bfrag[4][4];
  #pragma unroll
  for (int ct = 0; ct < 4; ++ct) {
    const _Float16* wrow = W2T + (ct * 16 + lcol) * MM + quad * 8;
    #pragma unroll
    for (int ks = 0; ks < 4; ++ks)
      bfrag[ct][ks] = *(const half8*)(wrow + ks * 32);
  }

  // P fragment for this wave's i: lane's A-frag k-slots (8 halfs per ks)
  H8 pv[4];
  {
    const _Float16* prow = P + i * MM + quad * 8;
    #pragma unroll
    for (int ks = 0; ks < 4; ++ks)
      pv[ks].v = *(const half8*)(prow + ks * 32);
  }

  float rmax[4] = {-1e30f, -1e30f, -1e30f, -1e30f};

  const _Float16* qptr = Q + (js * NTILE * 16 + lcol) * MM + quad * 8;

  const half2v hz2 = {(_Float16)0.f, (_Float16)0.f};
  const f32x4 zc = {0.f, 0.f, 0.f, 0.f};

  #pragma unroll 1
  for (int t = 0; t < NTILE; ++t) {
    H8 q[4];
    #pragma unroll
    for (int ks = 0; ks < 4; ++ks)
      q[ks].v = *(const half8*)(qptr + ks * 32);
    qptr += 16 * MM;

    f32x4 acc[4];
    #pragma unroll
    for (int ks = 0; ks < 4; ++ks) {
      // A-frag = relu(q - p): packed half2 (v_pk_sub_f16 + v_pk_max_f16)
      H8 s;
      #pragma unroll
      for (int r = 0; r < 4; ++r) {
        half2v d = q[ks].h2[r] - pv[ks].h2[r];
        s.h2[r] = __builtin_elementwise_max(d, hz2);
      }
      if (ks == 0) {
        #pragma unroll
        for (int ct = 0; ct < 4; ++ct)
          acc[ct] = __builtin_amdgcn_mfma_f32_16x16x32_f16(s.v, bfrag[ct][0], zc, 0, 0, 0);
      } else {
        #pragma unroll
        for (int ct = 0; ct < 4; ++ct)
          acc[ct] = __builtin_amdgcn_mfma_f32_16x16x32_f16(s.v, bfrag[ct][ks], acc[ct], 0, 0, 0);
      }
    }

    // C/D: col=lcol(+ct*16), row(j)=quad*4+reg
    #pragma unroll
    for (int ct = 0; ct < 4; ++ct) {
      const float m01 = fmaxf(acc[ct][0], acc[ct][1]);
      const float m23 = fmaxf(acc[ct][2], acc[ct][3]);
      rmax[ct] = fmaxf(rmax[ct], fmaxf(m01, m23));
    }
  }

  // combine quad-groups (different j rows, same col), then b2 + relu + atomic max
  #pragma unroll
  for (int ct = 0; ct < 4; ++ct) {
    float v = rmax[ct];
    v = fmaxf(v, __shfl_xor(v, 16, 64));
    v = fmaxf(v, __shfl_xor(v, 32, 64));
    v = fmaxf(v + b2[ct * 16 + lcol], 0.f);
    if (quad == 0)
      atomicMax((unsigned*)(out + i * HH + ct * 16 + lcol), __float_as_uint(v));
  }
}

extern "C" void kernel_launch(void* const* d_in, const int* in_sizes, int n_in,
                              void* d_out, int out_size, void* d_ws, size_t ws_size,
                              hipStream_t stream) {
  const float* hidden = (const float*)d_in[0];
  const float* gt     = (const float*)d_in[1];
  const float* We     = (const float*)d_in[2];
  const float* be     = (const float*)d_in[3];
  const float* W1     = (const float*)d_in[4];
  const float* b1     = (const float*)d_in[5];
  const float* W2     = (const float*)d_in[6];
  const float* b2     = (const float*)d_in[7];
  float* out = (float*)d_out;

  _Float16* Qh  = (_Float16*)d_ws;    // NN*MM fp16 (384KB)
  _Float16* Ph  = Qh + NN * MM;       // NN*MM fp16 (384KB)
  _Float16* W2T = Ph + NN * MM;       // HH*MM fp16 (16KB)

  precompute_kernel<<<NN, 128, 0, stream>>>(hidden, gt, We, be, W1, b1, W2, Qh, Ph, W2T, out);
  pairmlp_max_kernel<<<NIGRP * JSPLIT, 256, 0, stream>>>(Qh, Ph, W2T, b2, out);
}

// Round 8
// 114.434 us; speedup vs baseline: 1.4188x; 1.4188x over previous
//
#include <hip/hip_runtime.h>
#include <hip/hip_fp16.h>

// N=1536 T=20 H=64 E=16 M=128
// pre1[i,j] = Q[j] - P[i];  out[i] = max_j relu( relu(Q[j]-P[i]) @ W2 + b2 )
//
// R8: canonical LDS pipeline. Evidence R5->R6->R7: time monotone in MFMA-per-
// load-batch (48/32/16 -> 53.7/65.8/102us) regardless of occupancy => global
// load latency (~200-400cy) is never hidden by TLP or register prefetch.
// Fix: (a) Q-tiles staged to LDS via one global_load_lds(16B)/thread, ping-pong
// dbuf, barrier-pipelined => global latency off the critical path; (b) W2T in
// LDS, re-read per ks => frees the 64-reg bfrag that capped occupancy at
// 2 waves/SIMD; NI=2 now fits ~120 regs => 4 waves/SIMD; (c) Q/W2T stored
// granule-XOR-swizzled (pos = g ^ (row&15), 16B granules) by precompute:
// keeps global_load_lds contiguity AND spreads ds_read_b128 over all 8 bank
// groups (naive layout = all 64 lanes on one 4-bank group).

#define NN 1536
#define HH 64
#define EE 16
#define MM 128
#define TT 20
#define NI 2                 // i's per wave
#define IB 8                 // i's per block (4 waves * NI)
#define JSPLIT 8
#define NIGRP (NN / IB)      // 192 i-groups
#define NTILE (96 / JSPLIT)  // 12 j-tiles of 16 per block

typedef _Float16 half8 __attribute__((ext_vector_type(8)));
typedef float f32x4 __attribute__((ext_vector_type(4)));

__device__ __forceinline__ void async16(const void* g, void* l) {
  __builtin_amdgcn_global_load_lds(
      (const __attribute__((address_space(1))) unsigned int*)g,
      (__attribute__((address_space(3))) unsigned int*)l, 16, 0, 0);
}

// grid NN, block 128. Q (swizzled), P (plain), W2T (swizzled) fp16; out zeroed.
// Swizzle: within a 256B row, 16B-granule gm stored at position gm ^ (row&15).
__global__ __launch_bounds__(128) void precompute_kernel(
    const float* __restrict__ hidden, const float* __restrict__ gt,
    const float* __restrict__ We, const float* __restrict__ be,
    const float* __restrict__ W1, const float* __restrict__ b1,
    const float* __restrict__ W2,
    _Float16* __restrict__ Qs, _Float16* __restrict__ P,
    _Float16* __restrict__ W2Ts, float* __restrict__ out)
{
  const int j = blockIdx.x;
  const int m = threadIdx.x;
  const float* hrow = hidden + j * HH;
  float a = 0.f;
  #pragma unroll 8
  for (int h = 0; h < HH; ++h) a = fmaf(hrow[h], W1[h * MM + m], a);
  float ve0 = 0.f, ve1 = 0.f, cm = b1[m];
  #pragma unroll
  for (int e = 0; e < EE; ++e) {
    float w1e = W1[(HH + e) * MM + m];
    ve0 = fmaf(We[e], w1e, ve0);       // We[0][e]
    ve1 = fmaf(We[EE + e], w1e, ve1);  // We[1][e]
    cm  = fmaf(be[e], w1e, cm);
  }
  const float e0 = gt[j * (2 * TT) + 2 * (TT - 1)];
  const float e1 = gt[j * (2 * TT) + 2 * (TT - 1) + 1];
  const float p = fmaf(e0, ve0, e1 * ve1);
  P[j * MM + m] = (_Float16)p;
  const int swz = ((((m >> 3) ^ (j & 15)) << 3) | (m & 7));
  Qs[j * MM + swz] = (_Float16)(a + p + cm);
  if (j < HH) W2Ts[j * MM + swz] = (_Float16)W2[m * HH + j];  // W2T[col][k], swizzled
  if (m < HH) out[j * HH + m] = 0.f;
}

// grid NIGRP*JSPLIT (=1536), block 256 (4 waves). Wave w: i = blk8 + w*2 + {0,1}.
// No min-waves arg (R2 lesson); est. live ~120 regs -> 4 waves/SIMD naturally.
__global__ __launch_bounds__(256) void pairmlp_max_kernel(
    const _Float16* __restrict__ Qs, const _Float16* __restrict__ P,
    const _Float16* __restrict__ W2Ts, const float* __restrict__ b2,
    float* __restrict__ out)
{
  __shared__ __align__(16) _Float16 sW[HH * MM];       // 16KB, swizzled
  __shared__ __align__(16) _Float16 sQ[2][16 * MM];    // 2 x 4KB tiles, swizzled

  const int tid  = threadIdx.x;
  const int wave = tid >> 6;
  const int lane = tid & 63;
  const int quad = lane >> 4;
  const int lcol = lane & 15;
  const int ig = blockIdx.x % NIGRP;
  const int js = blockIdx.x / NIGRP;
  const int i0 = ig * IB + wave * NI;
  const int jt0 = js * NTILE;

  // stage W2T (16KB): 4 x 16B per thread; pattern = wave-uniform base + lane*16
  #pragma unroll
  for (int r = 0; r < 4; ++r)
    async16((const char*)W2Ts + tid * 16 + r * 4096, (char*)sW + tid * 16 + r * 4096);
  // stage tile 0 (4KB contiguous)
  async16((const char*)Qs + (size_t)jt0 * 4096 + tid * 16, (char*)sQ[0] + tid * 16);

  // P fragments (plain layout; content matches granule g = ks*4+quad)
  half8 pv[NI][4];
  #pragma unroll
  for (int ii = 0; ii < NI; ++ii) {
    const _Float16* prow = P + (i0 + ii) * MM + quad * 8;
    #pragma unroll
    for (int ks = 0; ks < 4; ++ks)
      pv[ii][ks] = *(const half8*)(prow + ks * 32);
  }

  // swizzled per-lane LDS element offsets, one per ks (same for Q rows & W2T rows)
  int soff[4];
  #pragma unroll
  for (int ks = 0; ks < 4; ++ks)
    soff[ks] = lcol * MM + ((((ks * 4 + quad) ^ lcol) & 15) << 3);

  float rmax[NI][4];
  #pragma unroll
  for (int ii = 0; ii < NI; ++ii)
    #pragma unroll
    for (int ct = 0; ct < 4; ++ct) rmax[ii][ct] = -1e30f;

  const half8 hz = 0;
  const f32x4 zc = {0.f, 0.f, 0.f, 0.f};

  __syncthreads();  // W2T + tile0 staged (drains vmcnt)

  #pragma unroll 2
  for (int t = 0; t < NTILE; ++t) {
    // stage tile t+1 into the other buffer (last iter: harmless restage of jt0)
    const int jn = (t + 1 < NTILE) ? (jt0 + t + 1) : jt0;
    async16((const char*)Qs + (size_t)jn * 4096 + tid * 16, (char*)sQ[(t + 1) & 1] + tid * 16);

    const _Float16* qb = sQ[t & 1];
    f32x4 acc[NI][4];
    #pragma unroll
    for (int ks = 0; ks < 4; ++ks) {
      const half8 qg  = *(const half8*)(qb + soff[ks]);
      const half8 bf0 = *(const half8*)(sW + soff[ks]);
      const half8 bf1 = *(const half8*)(sW + soff[ks] + 16 * MM);
      const half8 bf2 = *(const half8*)(sW + soff[ks] + 32 * MM);
      const half8 bf3 = *(const half8*)(sW + soff[ks] + 48 * MM);
      #pragma unroll
      for (int ii = 0; ii < NI; ++ii) {
        half8 s = qg - pv[ii][ks];
        s = __builtin_elementwise_max(s, hz);   // v_pk_sub_f16 + v_pk_max_f16
        if (ks == 0) {
          acc[ii][0] = __builtin_amdgcn_mfma_f32_16x16x32_f16(s, bf0, zc, 0, 0, 0);
          acc[ii][1] = __builtin_amdgcn_mfma_f32_16x16x32_f16(s, bf1, zc, 0, 0, 0);
          acc[ii][2] = __builtin_amdgcn_mfma_f32_16x16x32_f16(s, bf2, zc, 0, 0, 0);
          acc[ii][3] = __builtin_amdgcn_mfma_f32_16x16x32_f16(s, bf3, zc, 0, 0, 0);
        } else {
          acc[ii][0] = __builtin_amdgcn_mfma_f32_16x16x32_f16(s, bf0, acc[ii][0], 0, 0, 0);
          acc[ii][1] = __builtin_amdgcn_mfma_f32_16x16x32_f16(s, bf1, acc[ii][1], 0, 0, 0);
          acc[ii][2] = __builtin_amdgcn_mfma_f32_16x16x32_f16(s, bf2, acc[ii][2], 0, 0, 0);
          acc[ii][3] = __builtin_amdgcn_mfma_f32_16x16x32_f16(s, bf3, acc[ii][3], 0, 0, 0);
        }
      }
    }

    // C/D: col=lcol(+ct*16), row(j)=quad*4+reg
    #pragma unroll
    for (int ii = 0; ii < NI; ++ii)
      #pragma unroll
      for (int ct = 0; ct < 4; ++ct) {
        const float m01 = fmaxf(acc[ii][ct][0], acc[ii][ct][1]);
        const float m23 = fmaxf(acc[ii][ct][2], acc[ii][ct][3]);
        rmax[ii][ct] = fmaxf(rmax[ii][ct], fmaxf(m01, m23));
      }

    // one barrier per tile: staging of t+1 complete AND buf (t) free for t+2
    __syncthreads();
  }

  // combine quad-groups (different j rows), then b2 + relu + atomic max
  #pragma unroll
  for (int ii = 0; ii < NI; ++ii)
    #pragma unroll
    for (int ct = 0; ct < 4; ++ct) {
      float v = rmax[ii][ct];
      v = fmaxf(v, __shfl_xor(v, 16, 64));
      v = fmaxf(v, __shfl_xor(v, 32, 64));
      v = fmaxf(v + b2[ct * 16 + lcol], 0.f);
      if (quad == 0)
        atomicMax((unsigned*)(out + (i0 + ii) * HH + ct * 16 + lcol), __float_as_uint(v));
    }
}

extern "C" void kernel_launch(void* const* d_in, const int* in_sizes, int n_in,
                              void* d_out, int out_size, void* d_ws, size_t ws_size,
                              hipStream_t stream) {
  const float* hidden = (const float*)d_in[0];
  const float* gt     = (const float*)d_in[1];
  const float* We     = (const float*)d_in[2];
  const float* be     = (const float*)d_in[3];
  const float* W1     = (const float*)d_in[4];
  const float* b1     = (const float*)d_in[5];
  const float* W2     = (const float*)d_in[6];
  const float* b2     = (const float*)d_in[7];
  float* out = (float*)d_out;

  _Float16* Qs   = (_Float16*)d_ws;   // NN*MM fp16 swizzled (384KB)
  _Float16* Ph   = Qs + NN * MM;      // NN*MM fp16 plain    (384KB)
  _Float16* W2Ts = Ph + NN * MM;      // HH*MM fp16 swizzled (16KB)

  precompute_kernel<<<NN, 128, 0, stream>>>(hidden, gt, We, be, W1, b1, W2, Qs, Ph, W2Ts, out);
  pairmlp_max_kernel<<<NIGRP * JSPLIT, 256, 0, stream>>>(Qs, Ph, W2Ts, b2, out);
}